// Round 5
// baseline (66.703 us; speedup 1.0000x reference)
//
#include <hip/hip_runtime.h>
#include <math.h>

// ---------------------------------------------------------------------------
// DetectionLoss — exact-semantics anchor loss.
//
// ws layout (bytes):
//   [0    ) int   npos[96]
//   [1024 ) float sum_bce_pos[96]
//   [2048 ) float sum_ce[96]
//   [3072 ) float sum_sl1[96]
//   [4096 ) float tot[3]
//   [4112 ) int   dcount
//   [8192 ) uint  keys[2064384]   order-mapped BCE of negatives (0 = not neg)
// ---------------------------------------------------------------------------

#define BATCH 32
#define NBOX 20

#define KEY_OFS0 0
#define KEY_OFS1 1572864   // 32 * 128*128*3
#define KEY_OFS2 1966080   // + 32 * 64*64*3

__device__ __forceinline__ unsigned mapf(float f) {
    unsigned u = __float_as_uint(f);
    return (u & 0x80000000u) ? ~u : (u | 0x80000000u);
}
__device__ __forceinline__ float unmapf(unsigned k) {
    unsigned u = (k & 0x80000000u) ? (k & 0x7FFFFFFFu) : ~k;
    return __uint_as_float(u);
}

// Wave-aggregated LDS histogram add: one atomic per UNIQUE bin per wave.
// Cost ~ #unique bins among active lanes — cheap exactly when contention
// would be worst (few hot bins), and cheap when few lanes are active.
// Must be called by all lanes of the wave (ballot/shfl are wave-wide).
__device__ __forceinline__ void agg_hist_add(int* lhist, int bin, bool active)
{
    unsigned long long rem = __ballot(active);
    int lane = threadIdx.x & 63;
    while (rem) {
        int leader = (int)__ffsll((unsigned long long)rem) - 1;
        int lbin = __shfl(bin, leader, 64);
        unsigned long long same = __ballot(active && (bin == lbin));
        if (lane == leader) atomicAdd(&lhist[lbin], (int)__popcll(same));
        rem &= ~same;
    }
}

// ---------------------------------------------------------------------------
// Kernel 0: zero the small stats region.
// ---------------------------------------------------------------------------
__global__ __launch_bounds__(1024) void k_init(int* __restrict__ ws)
{
    for (int i = threadIdx.x; i < 1040; i += 1024) ws[i] = 0;
}

// ---------------------------------------------------------------------------
// Kernel 1: per-anchor assignment + BCE + pos-side losses.
// Boxes read via block-uniform global loads (scalarize to s_load) — no LDS.
// Division-free IoU argmax: best kept as rational (bi, bu).
// ---------------------------------------------------------------------------
__global__ __launch_bounds__(256) void k_assign(
    const float* __restrict__ pred0, const float* __restrict__ pred1,
    const float* __restrict__ pred2,
    const float* __restrict__ tboxes, const int* __restrict__ tlabels,
    int* __restrict__ nposA, float* __restrict__ sumbce,
    float* __restrict__ sumce, float* __restrict__ sumsl1,
    unsigned* __restrict__ keys)
{
    int bid = blockIdx.x;
    int l, rel;
    if (bid < 2048)      { l = 0; rel = bid; }
    else if (bid < 2560) { l = 1; rel = bid - 2048; }
    else                 { l = 2; rel = bid - 2560; }

    int lw, stridei, bpi, keyofs;
    const float* pred;
    if (l == 0)      { lw = 7; stridei = 8;  bpi = 64; pred = pred0; keyofs = KEY_OFS0; }
    else if (l == 1) { lw = 6; stridei = 16; bpi = 16; pred = pred1; keyofs = KEY_OFS1; }
    else             { lw = 5; stridei = 32; bpi = 4;  pred = pred2; keyofs = KEY_OFS2; }
    int W  = 1 << lw;
    int HW = W * W;
    int b  = rel / bpi;
    int pb = rel - b * bpi;
    int li = l * BATCH + b;
    int t  = threadIdx.x;
    int p  = pb * 256 + t;

    const float* bb = tboxes + b * 80;   // block-uniform base

    float fs = (float)stridei;
    float cx = ((p & (W - 1)) + 0.5f) * fs;
    float cy = ((p >> lw)     + 0.5f) * fs;
    float h0 = 0.75f * fs, h1 = 1.125f * fs, h2 = 1.5f * fs;
    float a0 = (2.f*h0)*(2.f*h0), a1 = (2.f*h1)*(2.f*h1), a2 = (2.f*h2)*(2.f*h2);

    // rational best: bi/bu, init -1/1 (first candidate always wins, incl. 0)
    float bi0 = -1.f, bu0 = 1.f, bi1 = -1.f, bu1 = 1.f, bi2 = -1.f, bu2 = 1.f;
    int   id0 = 0, id1 = 0, id2 = 0;

    #pragma unroll
    for (int m = 0; m < NBOX; ++m) {
        float bx0 = bb[4*m], by0 = bb[4*m+1], bx1 = bb[4*m+2], by1 = bb[4*m+3];
        float ab  = (bx1 - bx0) * (by1 - by0);
        float dx0 = cx - bx0, dx1 = bx1 - cx;
        float dy0 = cy - by0, dy1 = by1 - cy;
        {
            float ix = fminf(h0, dx0) + fminf(h0, dx1);
            float iy = fminf(h0, dy0) + fminf(h0, dy1);
            ix = fmaxf(ix, 0.f); iy = fmaxf(iy, 0.f);
            float inter = ix * iy;
            float uni   = fmaxf(a0 + ab - inter, 1e-8f);
            if (inter * bu0 > bi0 * uni) { bi0 = inter; bu0 = uni; id0 = m; }
        }
        {
            float ix = fminf(h1, dx0) + fminf(h1, dx1);
            float iy = fminf(h1, dy0) + fminf(h1, dy1);
            ix = fmaxf(ix, 0.f); iy = fmaxf(iy, 0.f);
            float inter = ix * iy;
            float uni   = fmaxf(a1 + ab - inter, 1e-8f);
            if (inter * bu1 > bi1 * uni) { bi1 = inter; bu1 = uni; id1 = m; }
        }
        {
            float ix = fminf(h2, dx0) + fminf(h2, dx1);
            float iy = fminf(h2, dy0) + fminf(h2, dy1);
            ix = fmaxf(ix, 0.f); iy = fmaxf(iy, 0.f);
            float inter = ix * iy;
            float uni   = fmaxf(a2 + ab - inter, 1e-8f);
            if (inter * bu2 > bi2 * uni) { bi2 = inter; bu2 = uni; id2 = m; }
        }
    }

    const float* pbase = pred + (size_t)b * 24 * HW;
    unsigned* kbase = keys + keyofs + (size_t)b * HW * 3;

    auto do_scale = [&](int s, float bi, float bu, int idx) {
        bool pos = bi >= 0.5f * bu;
        bool neg = bi < 0.4f * bu;
        float obj = pbase[(size_t)(s * 8 + 4) * HW + p];
        float sp  = fmaxf(obj, 0.f) + __logf(1.f + __expf(-fabsf(obj)));
        float bce = pos ? sp - obj : sp;
        kbase[s * HW + p] = neg ? mapf(bce) : 0u;   // coalesced per-s plane
        if (pos) {
            atomicAdd(&nposA[li], 1);
            atomicAdd(&sumbce[li], bce);
            float c0 = pbase[(size_t)(s * 8 + 5) * HW + p];
            float c1 = pbase[(size_t)(s * 8 + 6) * HW + p];
            float c2 = pbase[(size_t)(s * 8 + 7) * HW + p];
            float mx = fmaxf(c0, fmaxf(c1, c2));
            float lse = mx + __logf(__expf(c0 - mx) + __expf(c1 - mx) + __expf(c2 - mx));
            int lab = tlabels[b * 20 + idx] - 1;          // rare, divergent OK
            float cl = (lab == 0) ? c0 : ((lab == 1) ? c1 : c2);
            atomicAdd(&sumce[li], lse - cl);
            float ssum = 0.f;
            #pragma unroll
            for (int q = 0; q < 4; ++q) {
                float d  = pbase[(size_t)(s * 8 + q) * HW + p] - bb[4 * idx + q];
                float ad = fabsf(d);
                ssum += (ad < 1.f) ? 0.5f * d * d : ad - 0.5f;
            }
            atomicAdd(&sumsl1[li], ssum);
        }
    };
    do_scale(0, bi0, bu0, id0);
    do_scale(1, bi1, bu1, id1);
    do_scale(2, bi2, bu2, id2);
}

// ---------------------------------------------------------------------------
// Kernel 2: per-(level,image) exact top-K negative radix select + finalize.
// 96 blocks x 1024 threads. 4 count passes (wave-aggregated histogram — no
// same-bin LDS-atomic serialization) + 1 atomic-free sum sweep.
// ---------------------------------------------------------------------------
__global__ __launch_bounds__(1024) void k_select(
    const int* __restrict__ nposA, const float* __restrict__ sumbce,
    const float* __restrict__ sumce, const float* __restrict__ sumsl1,
    const unsigned* __restrict__ keys, float* __restrict__ tot,
    int* __restrict__ dcount, float* __restrict__ out)
{
    int li = blockIdx.x;
    int t  = threadIdx.x;
    int np = nposA[li];

    __shared__ int   lhist[256];
    __shared__ int   sufi[257];
    __shared__ int   wtot[4];
    __shared__ int   s_bin, s_want, s_K;
    __shared__ float fred[16];

    if (np > 0) {
        int l = li >> 5, b = li & 31;
        int HW, keyofs;
        if (l == 0)      { HW = 16384; keyofs = KEY_OFS0; }
        else if (l == 1) { HW = 4096;  keyofs = KEY_OFS1; }
        else             { HW = 1024;  keyofs = KEY_OFS2; }
        int N  = HW * 3;
        int N4 = N >> 2;    // multiple of 64 for all levels -> wave-uniform trips
        const uint4* kk4 = reinterpret_cast<const uint4*>(keys + keyofs + (size_t)b * N);

        unsigned prefix = 0;
        int K = 0, want = 0;
        int lane = t & 63;

        for (int pass = 0; pass < 4; ++pass) {
            if (t < 256) lhist[t] = 0;
            __syncthreads();

            int shift = 24 - 8 * pass;
            for (int i = t; i < N4; i += 1024) {
                uint4 k4 = kk4[i];
                unsigned ka[4] = {k4.x, k4.y, k4.z, k4.w};
                #pragma unroll
                for (int j = 0; j < 4; ++j) {
                    bool act;
                    int  bin;
                    if (pass == 0) { act = true; bin = (int)(ka[j] >> 24); }
                    else {
                        act = (ka[j] >> (shift + 8)) == prefix;
                        bin = (int)((ka[j] >> shift) & 255u);
                    }
                    agg_hist_add(lhist, bin, act);
                }
            }
            __syncthreads();

            // suffix scan of lhist using threads 0..255 (4 waves + cross-wave)
            int v = 0;
            if (t < 256) {
                v = lhist[t];
                for (int off = 1; off < 64; off <<= 1) {
                    int o = __shfl_down(v, off, 64);
                    if (lane + off < 64) v += o;
                }
                if (lane == 0) wtot[t >> 6] = v;
            }
            __syncthreads();
            if (t < 256) {
                int w = t >> 6, add = 0;
                for (int j = w + 1; j < 4; ++j) add += wtot[j];
                sufi[t] = v + add;
            }
            if (t == 0) sufi[256] = 0;
            __syncthreads();

            if (pass == 0) {
                if (t == 0) s_K = min(3 * np, sufi[128]);   // negs have top bit set
                __syncthreads();
                K = s_K; want = K;
                if (K == 0) break;
            }
            if (t < 256 && sufi[t] >= want && sufi[t + 1] < want) {
                s_bin  = t;
                s_want = want - sufi[t + 1];
            }
            __syncthreads();
            prefix = (prefix << 8) | (unsigned)s_bin;
            want   = s_want;
            __syncthreads();
        }

        float negsum = 0.f;
        if (K > 0) {
            unsigned T = prefix;   // exact K-th largest key
            float lsum = 0.f;
            for (int i = t; i < N4; i += 1024) {
                uint4 k4 = kk4[i];
                unsigned ka[4] = {k4.x, k4.y, k4.z, k4.w};
                #pragma unroll
                for (int j = 0; j < 4; ++j)
                    if (ka[j] > T) lsum += unmapf(ka[j]);
            }
            for (int off = 32; off > 0; off >>= 1) lsum += __shfl_down(lsum, off, 64);
            if (lane == 0) fred[t >> 6] = lsum;
            __syncthreads();
            if (t == 0) {
                float sb = 0.f;
                #pragma unroll
                for (int j = 0; j < 16; ++j) sb += fred[j];
                negsum = sb + (float)want * unmapf(T);   // ties: identical values
            }
        }

        if (t == 0) {
            int nsel = np + K;
            float obj_l = (sumbce[li] + negsum) / (float)nsel;
            float cls_l = sumce[li] / (float)np;
            float loc_l = sumsl1[li] / (float)(4 * np);
            atomicAdd(&tot[0], obj_l);
            atomicAdd(&tot[1], cls_l);
            atomicAdd(&tot[2], loc_l);
        }
    }

    // fused finalize: last block to arrive writes the output
    __threadfence();
    if (t == 0) {
        int prev = atomicAdd(dcount, 1);
        if (prev == 95) {
            __threadfence();
            float o  = atomicAdd(&tot[0], 0.f) * (1.f / BATCH);
            float c  = atomicAdd(&tot[1], 0.f) * (1.f / BATCH);
            float lo = atomicAdd(&tot[2], 0.f) * (1.f / BATCH);
            out[0] = o; out[1] = c; out[2] = lo; out[3] = o + c + 2.f * lo;
        }
    }
}

extern "C" void kernel_launch(void* const* d_in, const int* in_sizes, int n_in,
                              void* d_out, int out_size, void* d_ws, size_t ws_size,
                              hipStream_t stream) {
    const float* pred0   = (const float*)d_in[0];
    const float* pred1   = (const float*)d_in[1];
    const float* pred2   = (const float*)d_in[2];
    const float* tboxes  = (const float*)d_in[6];
    const int*   tlabels = (const int*)d_in[7];

    char* ws = (char*)d_ws;
    int*      nposA  = (int*)ws;
    float*    sumbce = (float*)(ws + 1024);
    float*    sumce  = (float*)(ws + 2048);
    float*    sumsl1 = (float*)(ws + 3072);
    float*    tot    = (float*)(ws + 4096);
    int*      dcount = (int*)(ws + 4112);
    unsigned* keys   = (unsigned*)(ws + 8192);

    hipLaunchKernelGGL(k_init, dim3(1), dim3(1024), 0, stream, (int*)ws);
    hipLaunchKernelGGL(k_assign, dim3(2688), dim3(256), 0, stream,
                       pred0, pred1, pred2, tboxes, tlabels,
                       nposA, sumbce, sumce, sumsl1, keys);
    hipLaunchKernelGGL(k_select, dim3(96), dim3(1024), 0, stream,
                       nposA, sumbce, sumce, sumsl1, keys, tot, dcount,
                       (float*)d_out);
}

// Round 6
// 63.045 us; speedup vs baseline: 1.0580x; 1.0580x over previous
//
#include <hip/hip_runtime.h>
#include <math.h>

// ---------------------------------------------------------------------------
// DetectionLoss — exact-semantics anchor loss.
//
// ws layout (bytes):
//   [0      ) int   npos[96]
//   [1024   ) float sum_bce_pos[96]
//   [2048   ) float sum_ce[96]
//   [3072   ) float sum_sl1[96]
//   [4096   ) float tot[3]
//   [4112   ) int   dcount
//   [8192   ) int   ghist[96*1024]   coarse top-10-bit key histograms (384 KB)
//   [401408 ) uint  keys[2064384]    order-mapped BCE of negatives (0 = not neg)
// ---------------------------------------------------------------------------

#define BATCH 32
#define NBOX 20

#define KEY_OFS0 0
#define KEY_OFS1 1572864   // 32 * 128*128*3
#define KEY_OFS2 1966080   // + 32 * 64*64*3

__device__ __forceinline__ unsigned mapf(float f) {
    unsigned u = __float_as_uint(f);
    return (u & 0x80000000u) ? ~u : (u | 0x80000000u);
}
__device__ __forceinline__ float unmapf(unsigned k) {
    unsigned u = (k & 0x80000000u) ? (k & 0x7FFFFFFFu) : ~k;
    return __uint_as_float(u);
}

// ---------------------------------------------------------------------------
// Kernel 0: zero ghist (96 KB-pages across 96 blocks) + stats (block 0).
// ---------------------------------------------------------------------------
__global__ __launch_bounds__(1024) void k_init(int* __restrict__ ws)
{
    int b = blockIdx.x, t = threadIdx.x;
    ws[2048 + b * 1024 + t] = 0;                    // ghist page
    if (b == 0) for (int i = t; i < 1040; i += 1024) ws[i] = 0;  // stats
}

// ---------------------------------------------------------------------------
// Kernel 1: per-anchor assignment + BCE + pos-side losses + fused coarse
// histogram of negative keys (top 10 bits) merged to global per-(level,img).
// ---------------------------------------------------------------------------
__global__ __launch_bounds__(256) void k_assign(
    const float* __restrict__ pred0, const float* __restrict__ pred1,
    const float* __restrict__ pred2,
    const float* __restrict__ tboxes, const int* __restrict__ tlabels,
    int* __restrict__ nposA, float* __restrict__ sumbce,
    float* __restrict__ sumce, float* __restrict__ sumsl1,
    unsigned* __restrict__ keys, int* __restrict__ ghist)
{
    int bid = blockIdx.x;
    int l, rel;
    if (bid < 2048)      { l = 0; rel = bid; }
    else if (bid < 2560) { l = 1; rel = bid - 2048; }
    else                 { l = 2; rel = bid - 2560; }

    int lw, stridei, bpi, keyofs;
    const float* pred;
    if (l == 0)      { lw = 7; stridei = 8;  bpi = 64; pred = pred0; keyofs = KEY_OFS0; }
    else if (l == 1) { lw = 6; stridei = 16; bpi = 16; pred = pred1; keyofs = KEY_OFS1; }
    else             { lw = 5; stridei = 32; bpi = 4;  pred = pred2; keyofs = KEY_OFS2; }
    int W  = 1 << lw;
    int HW = W * W;
    int b  = rel / bpi;
    int pb = rel - b * bpi;
    int li = l * BATCH + b;
    int t  = threadIdx.x;
    int p  = pb * 256 + t;

    __shared__ float sbb[NBOX * 4];
    __shared__ float sarea[NBOX];
    __shared__ int   slab[NBOX];
    __shared__ int   lh[1024];
    if (t < 80) sbb[t] = tboxes[b * 80 + t];
    if (t >= 128 && t < 148) slab[t - 128] = tlabels[b * 20 + (t - 128)];
    for (int i = t; i < 1024; i += 256) lh[i] = 0;
    __syncthreads();
    if (t < 20) sarea[t] = (sbb[4 * t + 2] - sbb[4 * t]) * (sbb[4 * t + 3] - sbb[4 * t + 1]);
    __syncthreads();

    float fs = (float)stridei;
    float cx = ((p & (W - 1)) + 0.5f) * fs;
    float cy = ((p >> lw)     + 0.5f) * fs;
    float h0 = 0.75f * fs, h1 = 1.125f * fs, h2 = 1.5f * fs;
    float a0 = (2.f*h0)*(2.f*h0), a1 = (2.f*h1)*(2.f*h1), a2 = (2.f*h2)*(2.f*h2);

    // rational best: bi/bu, init -1/1 (first candidate always wins, incl. 0)
    float bi0 = -1.f, bu0 = 1.f, bi1 = -1.f, bu1 = 1.f, bi2 = -1.f, bu2 = 1.f;
    int   id0 = 0, id1 = 0, id2 = 0;

    #pragma unroll
    for (int m = 0; m < NBOX; ++m) {
        float bx0 = sbb[4*m], by0 = sbb[4*m+1], bx1 = sbb[4*m+2], by1 = sbb[4*m+3];
        float ab  = sarea[m];
        float dx0 = cx - bx0, dx1 = bx1 - cx;
        float dy0 = cy - by0, dy1 = by1 - cy;
        {
            float ix = fminf(h0, dx0) + fminf(h0, dx1);
            float iy = fminf(h0, dy0) + fminf(h0, dy1);
            ix = fmaxf(ix, 0.f); iy = fmaxf(iy, 0.f);
            float inter = ix * iy;
            float uni   = fmaxf(a0 + ab - inter, 1e-8f);
            if (inter * bu0 > bi0 * uni) { bi0 = inter; bu0 = uni; id0 = m; }
        }
        {
            float ix = fminf(h1, dx0) + fminf(h1, dx1);
            float iy = fminf(h1, dy0) + fminf(h1, dy1);
            ix = fmaxf(ix, 0.f); iy = fmaxf(iy, 0.f);
            float inter = ix * iy;
            float uni   = fmaxf(a1 + ab - inter, 1e-8f);
            if (inter * bu1 > bi1 * uni) { bi1 = inter; bu1 = uni; id1 = m; }
        }
        {
            float ix = fminf(h2, dx0) + fminf(h2, dx1);
            float iy = fminf(h2, dy0) + fminf(h2, dy1);
            ix = fmaxf(ix, 0.f); iy = fmaxf(iy, 0.f);
            float inter = ix * iy;
            float uni   = fmaxf(a2 + ab - inter, 1e-8f);
            if (inter * bu2 > bi2 * uni) { bi2 = inter; bu2 = uni; id2 = m; }
        }
    }

    const float* pbase = pred + (size_t)b * 24 * HW;
    unsigned* kbase = keys + keyofs + (size_t)b * HW * 3;

    auto do_scale = [&](int s, float bi, float bu, int idx) {
        bool pos = bi >= 0.5f * bu;
        bool neg = bi < 0.4f * bu;
        float obj = pbase[(size_t)(s * 8 + 4) * HW + p];
        float sp  = fmaxf(obj, 0.f) + __logf(1.f + __expf(-fabsf(obj)));
        float bce = pos ? sp - obj : sp;
        unsigned key = neg ? mapf(bce) : 0u;
        kbase[s * HW + p] = key;                     // coalesced per-s plane
        if (neg) atomicAdd(&lh[key >> 22], 1);       // coarse 10-bit histogram
        if (pos) {
            atomicAdd(&nposA[li], 1);
            atomicAdd(&sumbce[li], bce);
            float c0 = pbase[(size_t)(s * 8 + 5) * HW + p];
            float c1 = pbase[(size_t)(s * 8 + 6) * HW + p];
            float c2 = pbase[(size_t)(s * 8 + 7) * HW + p];
            float mx = fmaxf(c0, fmaxf(c1, c2));
            float lse = mx + __logf(__expf(c0 - mx) + __expf(c1 - mx) + __expf(c2 - mx));
            int lab = slab[idx] - 1;
            float cl = (lab == 0) ? c0 : ((lab == 1) ? c1 : c2);
            atomicAdd(&sumce[li], lse - cl);
            float ssum = 0.f;
            #pragma unroll
            for (int q = 0; q < 4; ++q) {
                float d  = pbase[(size_t)(s * 8 + q) * HW + p] - sbb[4 * idx + q];
                float ad = fabsf(d);
                ssum += (ad < 1.f) ? 0.5f * d * d : ad - 0.5f;
            }
            atomicAdd(&sumsl1[li], ssum);
        }
    };
    do_scale(0, bi0, bu0, id0);
    do_scale(1, bi1, bu1, id1);
    do_scale(2, bi2, bu2, id2);

    // merge nonzero coarse bins to the per-(level,image) global histogram
    __syncthreads();
    int* gh = ghist + li * 1024;
    for (int i = t; i < 1024; i += 256) {
        int c = lh[i];
        if (c) atomicAdd(&gh[i], c);
    }
}

// ---------------------------------------------------------------------------
// Kernel 2: per-(level,image) exact top-K selection.
// Stage 0: scan prebuilt 1024-bin hist (no sweep).  Pass A/B: 2048-bin LDS
// radix over remaining 22 bits (only boundary-subset keys do atomics).
// Sweep C: atomic-free sum of keys > T.  Then finalize (last block -> out).
// ---------------------------------------------------------------------------
__global__ __launch_bounds__(1024) void k_finish(
    const int* __restrict__ nposA, const float* __restrict__ sumbce,
    const float* __restrict__ sumce, const float* __restrict__ sumsl1,
    const unsigned* __restrict__ keys, const int* __restrict__ ghist,
    float* __restrict__ tot, int* __restrict__ dcount, float* __restrict__ out)
{
    int li = blockIdx.x;
    int t  = threadIdx.x;
    int lane = t & 63, w = t >> 6;
    int np = nposA[li];

    __shared__ int   h2[2048];
    __shared__ int   wtot[16];
    __shared__ int   s_bin, s_want, s_negtot;
    __shared__ float fred[16];

    if (np > 0) {
        int l = li >> 5, b = li & 31;
        int HW, keyofs;
        if (l == 0)      { HW = 16384; keyofs = KEY_OFS0; }
        else if (l == 1) { HW = 4096;  keyofs = KEY_OFS1; }
        else             { HW = 1024;  keyofs = KEY_OFS2; }
        int N  = HW * 3;
        int N4 = N >> 2;
        const uint4* kk4 = reinterpret_cast<const uint4*>(keys + keyofs + (size_t)b * N);

        // ---- stage 0: suffix-scan the coarse 1024-bin histogram ----
        int c = ghist[li * 1024 + t];
        int v = c;
        #pragma unroll
        for (int off = 1; off < 64; off <<= 1) {
            int o = __shfl_down(v, off, 64);
            if (lane + off < 64) v += o;
        }
        if (lane == 0) wtot[w] = v;
        __syncthreads();
        int add = 0;
        for (int j = w + 1; j < 16; ++j) add += wtot[j];
        int S = v + add;                         // suffix incl. bin t
        if (t == 512) s_negtot = S;              // total negatives
        __syncthreads();
        int K = min(3 * np, s_negtot);
        float negsum = 0.f;

        if (K > 0) {
            if (S >= K && S - c < K) { s_bin = t; s_want = K - (S - c); }
            __syncthreads();
            unsigned B = (unsigned)s_bin;        // 10-bit prefix
            int want = s_want;

            // ---- pass A: bins = key bits [21:11], keys with (key>>22)==B ----
            h2[t] = 0; h2[t + 1024] = 0;
            __syncthreads();
            for (int i = t; i < N4; i += 1024) {
                uint4 k4 = kk4[i];
                unsigned ka[4] = {k4.x, k4.y, k4.z, k4.w};
                #pragma unroll
                for (int j = 0; j < 4; ++j)
                    if ((ka[j] >> 22) == B) atomicAdd(&h2[(ka[j] >> 11) & 2047u], 1);
            }
            __syncthreads();
            {   // suffix-scan 2048 bins (2 per thread, pair trick)
                int a0 = h2[2 * t], a1 = h2[2 * t + 1];
                int pr = a0 + a1;
                int pv = pr;
                #pragma unroll
                for (int off = 1; off < 64; off <<= 1) {
                    int o = __shfl_down(pv, off, 64);
                    if (lane + off < 64) pv += o;
                }
                if (lane == 0) wtot[w] = pv;
                __syncthreads();
                int ad2 = 0;
                for (int j = w + 1; j < 16; ++j) ad2 += wtot[j];
                int pairS = pv + ad2;            // S[2t]
                // S[2t+1] = pairS - a0 ; S[2t+2] = pairS - pr
                if (pairS >= want && pairS - a0 < want)      { s_bin = 2 * t;     s_want = want - (pairS - a0); }
                if (pairS - a0 >= want && pairS - pr < want) { s_bin = 2 * t + 1; s_want = want - (pairS - pr); }
            }
            __syncthreads();
            unsigned pfx21 = (B << 11) | (unsigned)s_bin;    // bits [31:11]
            int want2 = s_want;
            __syncthreads();

            // ---- pass B: bins = key bits [10:0], keys with (key>>11)==pfx21 ----
            h2[t] = 0; h2[t + 1024] = 0;
            __syncthreads();
            for (int i = t; i < N4; i += 1024) {
                uint4 k4 = kk4[i];
                unsigned ka[4] = {k4.x, k4.y, k4.z, k4.w};
                #pragma unroll
                for (int j = 0; j < 4; ++j)
                    if ((ka[j] >> 11) == pfx21) atomicAdd(&h2[ka[j] & 2047u], 1);
            }
            __syncthreads();
            {
                int a0 = h2[2 * t], a1 = h2[2 * t + 1];
                int pr = a0 + a1;
                int pv = pr;
                #pragma unroll
                for (int off = 1; off < 64; off <<= 1) {
                    int o = __shfl_down(pv, off, 64);
                    if (lane + off < 64) pv += o;
                }
                if (lane == 0) wtot[w] = pv;
                __syncthreads();
                int ad2 = 0;
                for (int j = w + 1; j < 16; ++j) ad2 += wtot[j];
                int pairS = pv + ad2;
                if (pairS >= want2 && pairS - a0 < want2)      { s_bin = 2 * t;     s_want = want2 - (pairS - a0); }
                if (pairS - a0 >= want2 && pairS - pr < want2) { s_bin = 2 * t + 1; s_want = want2 - (pairS - pr); }
            }
            __syncthreads();
            unsigned T = (pfx21 << 11) | (unsigned)s_bin;    // exact K-th largest
            int wantT = s_want;

            // ---- sweep C: atomic-free sum of keys strictly above T ----
            float lsum = 0.f;
            for (int i = t; i < N4; i += 1024) {
                uint4 k4 = kk4[i];
                unsigned ka[4] = {k4.x, k4.y, k4.z, k4.w};
                #pragma unroll
                for (int j = 0; j < 4; ++j)
                    if (ka[j] > T) lsum += unmapf(ka[j]);
            }
            #pragma unroll
            for (int off = 32; off > 0; off >>= 1) lsum += __shfl_down(lsum, off, 64);
            if (lane == 0) fred[w] = lsum;
            __syncthreads();
            if (t == 0) {
                float sb = 0.f;
                #pragma unroll
                for (int j = 0; j < 16; ++j) sb += fred[j];
                negsum = sb + (float)wantT * unmapf(T);      // ties: identical values
            }
        }

        if (t == 0) {
            int nsel = np + K;
            float obj_l = (sumbce[li] + negsum) / (float)nsel;
            float cls_l = sumce[li] / (float)np;
            float loc_l = sumsl1[li] / (float)(4 * np);
            atomicAdd(&tot[0], obj_l);
            atomicAdd(&tot[1], cls_l);
            atomicAdd(&tot[2], loc_l);
        }
    }

    // fused finalize: last block to arrive writes the output
    __threadfence();
    if (t == 0) {
        int prev = atomicAdd(dcount, 1);
        if (prev == 95) {
            __threadfence();
            float o  = atomicAdd(&tot[0], 0.f) * (1.f / BATCH);
            float cc = atomicAdd(&tot[1], 0.f) * (1.f / BATCH);
            float lo = atomicAdd(&tot[2], 0.f) * (1.f / BATCH);
            out[0] = o; out[1] = cc; out[2] = lo; out[3] = o + cc + 2.f * lo;
        }
    }
}

extern "C" void kernel_launch(void* const* d_in, const int* in_sizes, int n_in,
                              void* d_out, int out_size, void* d_ws, size_t ws_size,
                              hipStream_t stream) {
    const float* pred0   = (const float*)d_in[0];
    const float* pred1   = (const float*)d_in[1];
    const float* pred2   = (const float*)d_in[2];
    const float* tboxes  = (const float*)d_in[6];
    const int*   tlabels = (const int*)d_in[7];

    char* ws = (char*)d_ws;
    int*      nposA  = (int*)ws;
    float*    sumbce = (float*)(ws + 1024);
    float*    sumce  = (float*)(ws + 2048);
    float*    sumsl1 = (float*)(ws + 3072);
    float*    tot    = (float*)(ws + 4096);
    int*      dcount = (int*)(ws + 4112);
    int*      ghist  = (int*)(ws + 8192);
    unsigned* keys   = (unsigned*)(ws + 401408);

    hipLaunchKernelGGL(k_init, dim3(96), dim3(1024), 0, stream, (int*)ws);
    hipLaunchKernelGGL(k_assign, dim3(2688), dim3(256), 0, stream,
                       pred0, pred1, pred2, tboxes, tlabels,
                       nposA, sumbce, sumce, sumsl1, keys, ghist);
    hipLaunchKernelGGL(k_finish, dim3(96), dim3(1024), 0, stream,
                       nposA, sumbce, sumce, sumsl1, keys, ghist, tot, dcount,
                       (float*)d_out);
}